// Round 5
// baseline (254.008 us; speedup 1.0000x reference)
//
#include <hip/hip_runtime.h>
#include <math.h>

#define NQ 10
#define NL 4

typedef float v2f __attribute__((ext_vector_type(2)));

// ---------- packed complex arithmetic (VOP3P, 2 floats per instruction) ----------
// d = u * a (complex):  d = (ur*re - ui*im, ur*im + ui*re)
__device__ __forceinline__ v2f cmul(v2f u, v2f a) {
  v2f d;
  asm("v_pk_mul_f32 %0, %1, %2 op_sel_hi:[0,1]\n\t"
      "v_pk_fma_f32 %0, %1, %2, %0 op_sel:[1,1,0] op_sel_hi:[1,0,1] neg_lo:[0,1,0]"
      : "=&v"(d) : "v"(u), "v"(a));
  return d;
}
// d += u * a (complex)
__device__ __forceinline__ void cfma(v2f &d, v2f u, v2f a) {
  asm("v_pk_fma_f32 %0, %1, %2, %0 op_sel_hi:[0,1,1]\n\t"
      "v_pk_fma_f32 %0, %1, %2, %0 op_sel:[1,1,0] op_sel_hi:[1,0,1] neg_lo:[0,1,0]"
      : "+v"(d) : "v"(u), "v"(a));
}

// ---------- gates on TWO independent states (ILP pair) ----------
template<int RB>
__device__ __forceinline__ void gate_rbit2(v2f A[16], v2f B[16],
                                           v2f u00, v2f u01, v2f u10, v2f u11) {
#pragma unroll
  for (int r0 = 0; r0 < 16; ++r0) {
    if ((r0 >> RB) & 1) continue;
    const int r1 = r0 | (1 << RB);
    const v2f a0 = A[r0], a1 = A[r1];
    const v2f b0 = B[r0], b1 = B[r1];
    v2f na0 = cmul(u00, a0); v2f nb0 = cmul(u00, b0);
    cfma(na0, u01, a1);      cfma(nb0, u01, b1);
    v2f na1 = cmul(u10, a0); v2f nb1 = cmul(u10, b0);
    cfma(na1, u11, a1);      cfma(nb1, u11, b1);
    A[r0] = na0; A[r1] = na1;
    B[r0] = nb0; B[r1] = nb1;
  }
}

// lane-bit gate: batches of 4 regs per sample (16 shuffles in flight), then packed FMA
template<int LB>
__device__ __forceinline__ void gate_lbit2(v2f A[16], v2f B[16], v2f cS, v2f cP) {
#pragma unroll
  for (int h = 0; h < 4; ++h) {
    v2f pa[4], pb[4];
#pragma unroll
    for (int k = 0; k < 4; ++k) {
      const int r = h * 4 + k;
      pa[k].x = __shfl_xor(A[r].x, 1 << LB, 64);
      pa[k].y = __shfl_xor(A[r].y, 1 << LB, 64);
      pb[k].x = __shfl_xor(B[r].x, 1 << LB, 64);
      pb[k].y = __shfl_xor(B[r].y, 1 << LB, 64);
    }
#pragma unroll
    for (int k = 0; k < 4; ++k) {
      const int r = h * 4 + k;
      v2f na = cmul(cS, A[r]); cfma(na, cP, pa[k]); A[r] = na;
      v2f nb = cmul(cS, B[r]); cfma(nb, cP, pb[k]); B[r] = nb;
    }
  }
}

// ---------- whole CNOT ring as ONE linear permutation (HW-verified R2-R4):
// dst[r'][lane'] = src[gray4(r') ^ ((lane'&1)*12)][(lane'^(lane'>>1)) ^ ((r'&1)<<5)]
__device__ __forceinline__ void ring_comp(v2f a[16], int addr0, int addr1, bool odd) {
  float B[16];
#pragma unroll
  for (int g = 0; g < 16; ++g) {
    const int par = ((g ^ (g >> 1) ^ (g >> 2) ^ (g >> 3)) & 1);
    B[g] = __int_as_float(__builtin_amdgcn_ds_bpermute(par ? addr1 : addr0,
                                                       __float_as_int(a[g].x)));
  }
#pragma unroll
  for (int r = 0; r < 16; ++r) {
    const int g = (r ^ (r >> 1));
    a[r].x = odd ? B[g ^ 12] : B[g];
  }
#pragma unroll
  for (int g = 0; g < 16; ++g) {
    const int par = ((g ^ (g >> 1) ^ (g >> 2) ^ (g >> 3)) & 1);
    B[g] = __int_as_float(__builtin_amdgcn_ds_bpermute(par ? addr1 : addr0,
                                                       __float_as_int(a[g].y)));
  }
#pragma unroll
  for (int r = 0; r < 16; ++r) {
    const int g = (r ^ (r >> 1));
    a[r].y = odd ? B[g ^ 12] : B[g];
  }
}

// product-state encoding for one sample
__device__ __forceinline__ void encode(const float* __restrict__ xb, int lane, v2f a[16]) {
  float lfac;
  {
    float c, s;
    sincosf(0.5f * xb[9], &s, &c); lfac  = ((lane >> 0) & 1) ? s : c;
    sincosf(0.5f * xb[8], &s, &c); lfac *= ((lane >> 1) & 1) ? s : c;
    sincosf(0.5f * xb[7], &s, &c); lfac *= ((lane >> 2) & 1) ? s : c;
    sincosf(0.5f * xb[6], &s, &c); lfac *= ((lane >> 3) & 1) ? s : c;
    sincosf(0.5f * xb[5], &s, &c); lfac *= ((lane >> 4) & 1) ? s : c;
    sincosf(0.5f * xb[4], &s, &c); lfac *= ((lane >> 5) & 1) ? s : c;
  }
  float c0, s0, c1, s1, c2, s2, c3, s3;
  sincosf(0.5f * xb[0], &s0, &c0);
  sincosf(0.5f * xb[1], &s1, &c1);
  sincosf(0.5f * xb[2], &s2, &c2);
  sincosf(0.5f * xb[3], &s3, &c3);
#pragma unroll
  for (int r = 0; r < 16; ++r) {
    float f = lfac;                     // r bit rb <-> qubit 3-rb
    f *= ((r >> 0) & 1) ? s3 : c3;
    f *= ((r >> 1) & 1) ? s2 : c2;
    f *= ((r >> 2) & 1) ? s1 : c1;
    f *= ((r >> 3) & 1) ? s0 : c0;
    a[r].x = f;
    a[r].y = 0.f;
  }
}

// measurement for one sample: z[0..9]
__device__ __forceinline__ void measure(const v2f a[16], int lane, float z[NQ]) {
  float p[16];
#pragma unroll
  for (int r = 0; r < 16; ++r) p[r] = a[r].x * a[r].x + a[r].y * a[r].y;
#pragma unroll
  for (int q = 0; q < 4; ++q) {
    const int rb = 3 - q;
    float acc = 0.f;
#pragma unroll
    for (int r = 0; r < 16; ++r) acc += ((r >> rb) & 1) ? -p[r] : p[r];
    z[q] = acc;
  }
  float P = 0.f;
#pragma unroll
  for (int r = 0; r < 16; ++r) P += p[r];
#pragma unroll
  for (int q = 4; q < NQ; ++q) {
    const int lb = 9 - q;
    z[q] = ((lane >> lb) & 1) ? -P : P;
  }
#pragma unroll
  for (int q = 0; q < NQ; ++q) {
    float v = z[q];
#pragma unroll
    for (int m = 1; m < 64; m <<= 1) v += __shfl_xor(v, m, 64);
    z[q] = v;
  }
}

__global__ __launch_bounds__(256, 4) void qsim_kernel(const float* __restrict__ x,
                                                      const float* __restrict__ w,
                                                      float* __restrict__ out,
                                                      int batch) {
  // ---- per-block: the 40 shared Rot matrices into LDS
  __shared__ float gsh[NL * NQ * 8];
  const int tid = threadIdx.x;
  if (tid < NL * NQ) {
    const float phi = w[tid * 3 + 0];
    const float th  = w[tid * 3 + 1];
    const float om  = w[tid * 3 + 2];
    float c, s, cp, sp, cm, sm;
    sincosf(0.5f * th, &s, &c);
    sincosf(-0.5f * (phi + om), &sp, &cp);
    sincosf(0.5f * (phi - om), &sm, &cm);
    float* g = &gsh[tid * 8];
    g[0] = cp * c;  g[1] = sp * c;
    g[2] = -cm * s; g[3] = -sm * s;
    g[4] = cm * s;  g[5] = -sm * s;
    g[6] = cp * c;  g[7] = -sp * c;
  }
  __syncthreads();

  // two samples per wave
  const int wid = (int)blockIdx.x * (blockDim.x >> 6) + (tid >> 6);
  const int s0 = wid * 2, s1 = wid * 2 + 1;
  const int lane = tid & 63;
  if (s0 >= batch) return;

  const int addr0 = 4 * (lane ^ (lane >> 1));
  const int addr1 = addr0 ^ 128;
  const bool lodd = (lane & 1);

  v2f A[16], B[16];
  encode(x + s0 * NQ, lane, A);
  encode(x + s1 * NQ, lane, B);

  // ---- layers
#pragma unroll
  for (int l = 0; l < NL; ++l) {
    const float* gl = &gsh[l * NQ * 8];

#pragma unroll
    for (int q = 0; q < 4; ++q) {
      const v2f* gv = (const v2f*)(gl + q * 8);
      const v2f u00 = gv[0], u01 = gv[1], u10 = gv[2], u11 = gv[3];
      if (q == 0)      gate_rbit2<3>(A, B, u00, u01, u10, u11);
      else if (q == 1) gate_rbit2<2>(A, B, u00, u01, u10, u11);
      else if (q == 2) gate_rbit2<1>(A, B, u00, u01, u10, u11);
      else             gate_rbit2<0>(A, B, u00, u01, u10, u11);
    }
#pragma unroll
    for (int q = 4; q < 10; ++q) {
      const v2f* gv = (const v2f*)(gl + q * 8);
      const bool hb = (lane >> (9 - q)) & 1;
      const v2f cS = hb ? gv[3] : gv[0];
      const v2f cP = hb ? gv[2] : gv[1];
      if (q == 4)      gate_lbit2<5>(A, B, cS, cP);
      else if (q == 5) gate_lbit2<4>(A, B, cS, cP);
      else if (q == 6) gate_lbit2<3>(A, B, cS, cP);
      else if (q == 7) gate_lbit2<2>(A, B, cS, cP);
      else if (q == 8) gate_lbit2<1>(A, B, cS, cP);
      else             gate_lbit2<0>(A, B, cS, cP);
    }

    ring_comp(A, addr0, addr1, lodd);
    ring_comp(B, addr0, addr1, lodd);
  }

  // ---- measurement (two samples)
  float z0[NQ], z1[NQ];
  measure(A, lane, z0);
  measure(B, lane, z1);

  if (lane == 0) {
#pragma unroll
    for (int q = 0; q < NQ; ++q) out[s0 * NQ + q] = z0[q];
  } else if (lane == 1) {
#pragma unroll
    for (int q = 0; q < NQ; ++q) out[s1 * NQ + q] = z1[q];
  }
}

extern "C" void kernel_launch(void* const* d_in, const int* in_sizes, int n_in,
                              void* d_out, int out_size, void* d_ws, size_t ws_size,
                              hipStream_t stream) {
  const float* x = (const float*)d_in[0];
  const float* w = (const float*)d_in[1];
  float* out = (float*)d_out;
  const int batch = in_sizes[0] / NQ;
  const int waves_per_block = 256 / 64;
  const int samples_per_block = waves_per_block * 2;
  const int grid = (batch + samples_per_block - 1) / samples_per_block;
  hipLaunchKernelGGL(qsim_kernel, dim3(grid), dim3(256), 0, stream, x, w, out, batch);
}

// Round 6
// 198.049 us; speedup vs baseline: 1.2826x; 1.2826x over previous
//
#include <hip/hip_runtime.h>
#include <math.h>

#define NQ 10
#define NL 4

typedef float v2f __attribute__((ext_vector_type(2)));

// ---------- packed complex arithmetic (VOP3P) ----------
// NOTE (R4): v_pk_* is FLOP-rate-limited (157 TF incl. packed) — it halves
// instruction count, not FMA cycles. Kept for issue-slot savings.
__device__ __forceinline__ v2f cmul(v2f u, v2f a) {
  v2f d;
  asm("v_pk_mul_f32 %0, %1, %2 op_sel_hi:[0,1]\n\t"
      "v_pk_fma_f32 %0, %1, %2, %0 op_sel:[1,1,0] op_sel_hi:[1,0,1] neg_lo:[0,1,0]"
      : "=&v"(d) : "v"(u), "v"(a));
  return d;
}
__device__ __forceinline__ void cfma(v2f &d, v2f u, v2f a) {
  asm("v_pk_fma_f32 %0, %1, %2, %0 op_sel_hi:[0,1,1]\n\t"
      "v_pk_fma_f32 %0, %1, %2, %0 op_sel:[1,1,0] op_sel_hi:[1,0,1] neg_lo:[0,1,0]"
      : "+v"(d) : "v"(u), "v"(a));
}

// ---------- gates on TWO independent states (ILP pair) ----------
template<int RB>
__device__ __forceinline__ void gate_rbit2(v2f A[16], v2f B[16],
                                           v2f u00, v2f u01, v2f u10, v2f u11) {
#pragma unroll
  for (int r0 = 0; r0 < 16; ++r0) {
    if ((r0 >> RB) & 1) continue;
    const int r1 = r0 | (1 << RB);
    const v2f a0 = A[r0], a1 = A[r1];
    const v2f b0 = B[r0], b1 = B[r1];
    v2f na0 = cmul(u00, a0); v2f nb0 = cmul(u00, b0);
    cfma(na0, u01, a1);      cfma(nb0, u01, b1);
    v2f na1 = cmul(u10, a0); v2f nb1 = cmul(u10, b0);
    cfma(na1, u11, a1);      cfma(nb1, u11, b1);
    A[r0] = na0; A[r1] = na1;
    B[r0] = nb0; B[r1] = nb1;
  }
}

// lane-bit gate: batches of 4 regs per sample (16 shuffles in flight), then packed FMA
template<int LB>
__device__ __forceinline__ void gate_lbit2(v2f A[16], v2f B[16], v2f cS, v2f cP) {
#pragma unroll
  for (int h = 0; h < 4; ++h) {
    v2f pa[4], pb[4];
#pragma unroll
    for (int k = 0; k < 4; ++k) {
      const int r = h * 4 + k;
      pa[k].x = __shfl_xor(A[r].x, 1 << LB, 64);
      pa[k].y = __shfl_xor(A[r].y, 1 << LB, 64);
      pb[k].x = __shfl_xor(B[r].x, 1 << LB, 64);
      pb[k].y = __shfl_xor(B[r].y, 1 << LB, 64);
    }
#pragma unroll
    for (int k = 0; k < 4; ++k) {
      const int r = h * 4 + k;
      v2f na = cmul(cS, A[r]); cfma(na, cP, pa[k]); A[r] = na;
      v2f nb = cmul(cS, B[r]); cfma(nb, cP, pb[k]); B[r] = nb;
    }
  }
}

// ---------- whole CNOT ring as ONE linear permutation (HW-verified R2-R5):
// dst[r'][lane'] = src[gray4(r') ^ ((lane'&1)*12)][(lane'^(lane'>>1)) ^ ((r'&1)<<5)]
// Interleaves both samples' components for deeper LDS-pipe batches.
__device__ __forceinline__ void ring_one(float a[], int stride_unused, int addr0, int addr1, bool odd) {
  (void)stride_unused;
  float B[16];
#pragma unroll
  for (int g = 0; g < 16; ++g) {
    const int par = ((g ^ (g >> 1) ^ (g >> 2) ^ (g >> 3)) & 1);
    B[g] = __int_as_float(__builtin_amdgcn_ds_bpermute(par ? addr1 : addr0,
                                                       __float_as_int(a[g])));
  }
#pragma unroll
  for (int r = 0; r < 16; ++r) {
    const int g = (r ^ (r >> 1));
    a[r] = odd ? B[g ^ 12] : B[g];
  }
}

__device__ __forceinline__ void ring_comp2(v2f A[16], v2f B[16],
                                           int addr0, int addr1, bool odd) {
  float t0[16], t1[16];
#pragma unroll
  for (int r = 0; r < 16; ++r) { t0[r] = A[r].x; t1[r] = B[r].x; }
  ring_one(t0, 0, addr0, addr1, odd);
  ring_one(t1, 0, addr0, addr1, odd);
#pragma unroll
  for (int r = 0; r < 16; ++r) { A[r].x = t0[r]; B[r].x = t1[r]; }
#pragma unroll
  for (int r = 0; r < 16; ++r) { t0[r] = A[r].y; t1[r] = B[r].y; }
  ring_one(t0, 0, addr0, addr1, odd);
  ring_one(t1, 0, addr0, addr1, odd);
#pragma unroll
  for (int r = 0; r < 16; ++r) { A[r].y = t0[r]; B[r].y = t1[r]; }
}

// product-state encoding for one sample
__device__ __forceinline__ void encode(const float* __restrict__ xb, int lane, v2f a[16]) {
  float lfac;
  {
    float c, s;
    sincosf(0.5f * xb[9], &s, &c); lfac  = ((lane >> 0) & 1) ? s : c;
    sincosf(0.5f * xb[8], &s, &c); lfac *= ((lane >> 1) & 1) ? s : c;
    sincosf(0.5f * xb[7], &s, &c); lfac *= ((lane >> 2) & 1) ? s : c;
    sincosf(0.5f * xb[6], &s, &c); lfac *= ((lane >> 3) & 1) ? s : c;
    sincosf(0.5f * xb[5], &s, &c); lfac *= ((lane >> 4) & 1) ? s : c;
    sincosf(0.5f * xb[4], &s, &c); lfac *= ((lane >> 5) & 1) ? s : c;
  }
  float c0, s0, c1, s1, c2, s2, c3, s3;
  sincosf(0.5f * xb[0], &s0, &c0);
  sincosf(0.5f * xb[1], &s1, &c1);
  sincosf(0.5f * xb[2], &s2, &c2);
  sincosf(0.5f * xb[3], &s3, &c3);
#pragma unroll
  for (int r = 0; r < 16; ++r) {
    float f = lfac;                     // r bit rb <-> qubit 3-rb
    f *= ((r >> 0) & 1) ? s3 : c3;
    f *= ((r >> 1) & 1) ? s2 : c2;
    f *= ((r >> 2) & 1) ? s1 : c1;
    f *= ((r >> 3) & 1) ? s0 : c0;
    a[r].x = f;
    a[r].y = 0.f;
  }
}

// measurement for one sample: z[0..9] (valid in lane 0 after reduction)
__device__ __forceinline__ void measure(const v2f a[16], int lane, float z[NQ]) {
  float p[16];
#pragma unroll
  for (int r = 0; r < 16; ++r) p[r] = a[r].x * a[r].x + a[r].y * a[r].y;
#pragma unroll
  for (int q = 0; q < 4; ++q) {
    const int rb = 3 - q;
    float acc = 0.f;
#pragma unroll
    for (int r = 0; r < 16; ++r) acc += ((r >> rb) & 1) ? -p[r] : p[r];
    z[q] = acc;
  }
  float P = 0.f;
#pragma unroll
  for (int r = 0; r < 16; ++r) P += p[r];
#pragma unroll
  for (int q = 4; q < NQ; ++q) {
    const int lb = 9 - q;
    z[q] = ((lane >> lb) & 1) ? -P : P;
  }
#pragma unroll
  for (int q = 0; q < NQ; ++q) {
    float v = z[q];
#pragma unroll
    for (int m = 1; m < 64; m <<= 1) v += __shfl_xor(v, m, 64);
    z[q] = v;
  }
}

__global__ __launch_bounds__(256) void qsim_kernel(const float* __restrict__ x,
                                                   const float* __restrict__ w,
                                                   float* __restrict__ out,
                                                   int batch) {
  // ---- per-block: the 40 shared Rot matrices into LDS
  __shared__ float gsh[NL * NQ * 8];
  const int tid = threadIdx.x;
  if (tid < NL * NQ) {
    const float phi = w[tid * 3 + 0];
    const float th  = w[tid * 3 + 1];
    const float om  = w[tid * 3 + 2];
    float c, s, cp, sp, cm, sm;
    sincosf(0.5f * th, &s, &c);
    sincosf(-0.5f * (phi + om), &sp, &cp);
    sincosf(0.5f * (phi - om), &sm, &cm);
    float* g = &gsh[tid * 8];
    g[0] = cp * c;  g[1] = sp * c;
    g[2] = -cm * s; g[3] = -sm * s;
    g[4] = cm * s;  g[5] = -sm * s;
    g[6] = cp * c;  g[7] = -sp * c;
  }
  __syncthreads();

  // two samples per wave
  const int wid = (int)blockIdx.x * (blockDim.x >> 6) + (tid >> 6);
  const int s0 = wid * 2, s1 = wid * 2 + 1;
  const int lane = tid & 63;
  if (s0 >= batch) return;

  const int addr0 = 4 * (lane ^ (lane >> 1));
  const int addr1 = addr0 ^ 128;
  const bool lodd = (lane & 1);

  v2f A[16], B[16];
  encode(x + s0 * NQ, lane, A);
  encode(x + s1 * NQ, lane, B);

  // ---- layers
#pragma unroll
  for (int l = 0; l < NL; ++l) {
    const float* gl = &gsh[l * NQ * 8];

#pragma unroll
    for (int q = 0; q < 4; ++q) {
      const v2f* gv = (const v2f*)(gl + q * 8);
      const v2f u00 = gv[0], u01 = gv[1], u10 = gv[2], u11 = gv[3];
      if (q == 0)      gate_rbit2<3>(A, B, u00, u01, u10, u11);
      else if (q == 1) gate_rbit2<2>(A, B, u00, u01, u10, u11);
      else if (q == 2) gate_rbit2<1>(A, B, u00, u01, u10, u11);
      else             gate_rbit2<0>(A, B, u00, u01, u10, u11);
    }
#pragma unroll
    for (int q = 4; q < 10; ++q) {
      const v2f* gv = (const v2f*)(gl + q * 8);
      const bool hb = (lane >> (9 - q)) & 1;
      const v2f cS = hb ? gv[3] : gv[0];
      const v2f cP = hb ? gv[2] : gv[1];
      if (q == 4)      gate_lbit2<5>(A, B, cS, cP);
      else if (q == 5) gate_lbit2<4>(A, B, cS, cP);
      else if (q == 6) gate_lbit2<3>(A, B, cS, cP);
      else if (q == 7) gate_lbit2<2>(A, B, cS, cP);
      else if (q == 8) gate_lbit2<1>(A, B, cS, cP);
      else             gate_lbit2<0>(A, B, cS, cP);
    }

    ring_comp2(A, B, addr0, addr1, lodd);
  }

  // ---- measurement (two samples)
  float z0[NQ], z1[NQ];
  measure(A, lane, z0);
  measure(B, lane, z1);

  if (lane == 0) {
#pragma unroll
    for (int q = 0; q < NQ; ++q) out[s0 * NQ + q] = z0[q];
  } else if (lane == 1) {
#pragma unroll
    for (int q = 0; q < NQ; ++q) out[s1 * NQ + q] = z1[q];
  }
}

extern "C" void kernel_launch(void* const* d_in, const int* in_sizes, int n_in,
                              void* d_out, int out_size, void* d_ws, size_t ws_size,
                              hipStream_t stream) {
  const float* x = (const float*)d_in[0];
  const float* w = (const float*)d_in[1];
  float* out = (float*)d_out;
  const int batch = in_sizes[0] / NQ;
  const int waves_per_block = 256 / 64;
  const int samples_per_block = waves_per_block * 2;
  const int grid = (batch + samples_per_block - 1) / samples_per_block;
  hipLaunchKernelGGL(qsim_kernel, dim3(grid), dim3(256), 0, stream, x, w, out, batch);
}

// Round 8
// 137.510 us; speedup vs baseline: 1.8472x; 1.4403x over previous
//
#include <hip/hip_runtime.h>
#include <math.h>

#define NQ 10
#define NL 4

typedef float v2f __attribute__((ext_vector_type(2)));

// ---------- cross-lane primitives (all R2-verified on HW) ----------
template<int CTRL>
__device__ __forceinline__ float dppx(float v) {  // quad_perm DPP (VALU pipe)
  return __int_as_float(__builtin_amdgcn_update_dpp(0, __float_as_int(v), CTRL, 0xF, 0xF, true));
}
template<int OFF>
__device__ __forceinline__ float swzx(float v) {  // ds_swizzle (DS pipe, pattern op)
  return __int_as_float(__builtin_amdgcn_ds_swizzle(__float_as_int(v), OFF));
}
__device__ __forceinline__ void pl16swap(float &a, float &b) {  // VALU
  asm("v_permlane16_swap_b32 %0, %1" : "+v"(a), "+v"(b));
}
__device__ __forceinline__ void pl32swap(float &a, float &b) {  // VALU
  asm("v_permlane32_swap_b32 %0, %1" : "+v"(a), "+v"(b));
}

// partner fetch for lane-bit LB in {0,1,2,3}: xor1/2 on VALU, xor4/8 on DS
template<int LB>
__device__ __forceinline__ float part(float v) {
  if constexpr (LB == 0) return dppx<0xB1>(v);        // quad_perm xor1
  else if constexpr (LB == 1) return dppx<0x4E>(v);   // quad_perm xor2
  else if constexpr (LB == 2) return swzx<0x101F>(v); // BitMode xor4
  else return swzx<0x201F>(v);                        // BitMode xor8
}

// ---------- packed complex arithmetic (VOP3P, R4-verified) ----------
__device__ __forceinline__ v2f cmul(v2f u, v2f a) {
  v2f d;
  asm("v_pk_mul_f32 %0, %1, %2 op_sel_hi:[0,1]\n\t"
      "v_pk_fma_f32 %0, %1, %2, %0 op_sel:[1,1,0] op_sel_hi:[1,0,1] neg_lo:[0,1,0]"
      : "=&v"(d) : "v"(u), "v"(a));
  return d;
}
__device__ __forceinline__ void cfma(v2f &d, v2f u, v2f a) {
  asm("v_pk_fma_f32 %0, %1, %2, %0 op_sel_hi:[0,1,1]\n\t"
      "v_pk_fma_f32 %0, %1, %2, %0 op_sel:[1,1,0] op_sel_hi:[1,0,1] neg_lo:[0,1,0]"
      : "+v"(d) : "v"(u), "v"(a));
}

// ---------- gates ----------
// register-bit qubit: pure packed FMA (R4-verified)
template<int RB>
__device__ __forceinline__ void gate_rbit(v2f a[16], v2f u00, v2f u01, v2f u10, v2f u11) {
#pragma unroll
  for (int r0 = 0; r0 < 16; ++r0) {
    if ((r0 >> RB) & 1) continue;
    const int r1 = r0 | (1 << RB);
    const v2f a0 = a[r0], a1 = a[r1];
    v2f n0 = cmul(u00, a0); cfma(n0, u01, a1);
    v2f n1 = cmul(u10, a0); cfma(n1, u11, a1);
    a[r0] = n0;
    a[r1] = n1;
  }
}

// lane-bit gate for LB in {0..3}: partner fetch via part<>, batches of 4 regs.
// cS = (hi ? u11 : u00), cP = (hi ? u10 : u01), selected per lane by caller.
template<int LB>
__device__ __forceinline__ void gate_part(v2f a[16], v2f cS, v2f cP) {
#pragma unroll
  for (int h = 0; h < 4; ++h) {
    v2f p[4];
#pragma unroll
    for (int k = 0; k < 4; ++k) {
      const int r = h * 4 + k;
      p[k].x = part<LB>(a[r].x);
      p[k].y = part<LB>(a[r].y);
    }
#pragma unroll
    for (int k = 0; k < 4; ++k) {
      const int r = h * 4 + k;
      v2f n = cmul(cS, a[r]); cfma(n, cP, p[k]);
      a[r] = n;
    }
  }
}

// lane-bit gate for bit4 (IS32=false) / bit5 (IS32=true) via permlane swaps (VALU only).
// After swap with a=b=v: lo holds bit=0 data, hi holds bit=1 data, in all lanes (R2-verified).
// cL = (hi ? u10 : u00), cH = (hi ? u11 : u01), selected per lane by caller.
template<bool IS32>
__device__ __forceinline__ void gate_swap(v2f a[16], v2f cL, v2f cH) {
#pragma unroll
  for (int r = 0; r < 16; ++r) {
    float lx = a[r].x, hx = a[r].x;
    float ly = a[r].y, hy = a[r].y;
    if constexpr (IS32) { pl32swap(lx, hx); pl32swap(ly, hy); }
    else                { pl16swap(lx, hx); pl16swap(ly, hy); }
    v2f lo, hi;
    lo.x = lx; lo.y = ly;
    hi.x = hx; hi.y = hy;
    v2f n = cmul(cL, lo); cfma(n, cH, hi);
    a[r] = n;
  }
}

// ---------- whole CNOT ring as ONE linear permutation (HW-verified R2-R6):
// dst[r'][lane'] = src[gray4(r') ^ ((lane'&1)*12)][(lane'^(lane'>>1)) ^ ((r'&1)<<5)]
__device__ __forceinline__ void ring_comp(v2f a[16], int addr0, int addr1, bool odd) {
  float B[16];
#pragma unroll
  for (int g = 0; g < 16; ++g) {
    const int par = ((g ^ (g >> 1) ^ (g >> 2) ^ (g >> 3)) & 1);
    B[g] = __int_as_float(__builtin_amdgcn_ds_bpermute(par ? addr1 : addr0,
                                                       __float_as_int(a[g].x)));
  }
#pragma unroll
  for (int r = 0; r < 16; ++r) {
    const int g = (r ^ (r >> 1));
    a[r].x = odd ? B[g ^ 12] : B[g];
  }
#pragma unroll
  for (int g = 0; g < 16; ++g) {
    const int par = ((g ^ (g >> 1) ^ (g >> 2) ^ (g >> 3)) & 1);
    B[g] = __int_as_float(__builtin_amdgcn_ds_bpermute(par ? addr1 : addr0,
                                                       __float_as_int(a[g].y)));
  }
#pragma unroll
  for (int r = 0; r < 16; ++r) {
    const int g = (r ^ (r >> 1));
    a[r].y = odd ? B[g ^ 12] : B[g];
  }
}

// full 64-lane sum on cheap pipes (R2-verified)
__device__ __forceinline__ float wsum(float v) {
  v += dppx<0xB1>(v);
  v += dppx<0x4E>(v);
  v += swzx<0x101F>(v);
  v += swzx<0x201F>(v);
  { float a = v, b = v; pl16swap(a, b); v = a + b; }
  { float a = v, b = v; pl32swap(a, b); v = a + b; }
  return v;
}

// product-state encoding (R4-verified)
__device__ __forceinline__ void encode(const float* __restrict__ xb, int lane, v2f a[16]) {
  float lfac;
  {
    float c, s;
    sincosf(0.5f * xb[9], &s, &c); lfac  = ((lane >> 0) & 1) ? s : c;
    sincosf(0.5f * xb[8], &s, &c); lfac *= ((lane >> 1) & 1) ? s : c;
    sincosf(0.5f * xb[7], &s, &c); lfac *= ((lane >> 2) & 1) ? s : c;
    sincosf(0.5f * xb[6], &s, &c); lfac *= ((lane >> 3) & 1) ? s : c;
    sincosf(0.5f * xb[5], &s, &c); lfac *= ((lane >> 4) & 1) ? s : c;
    sincosf(0.5f * xb[4], &s, &c); lfac *= ((lane >> 5) & 1) ? s : c;
  }
  float c0, s0, c1, s1, c2, s2, c3, s3;
  sincosf(0.5f * xb[0], &s0, &c0);
  sincosf(0.5f * xb[1], &s1, &c1);
  sincosf(0.5f * xb[2], &s2, &c2);
  sincosf(0.5f * xb[3], &s3, &c3);
#pragma unroll
  for (int r = 0; r < 16; ++r) {
    float f = lfac;                     // r bit rb <-> qubit 3-rb
    f *= ((r >> 0) & 1) ? s3 : c3;
    f *= ((r >> 1) & 1) ? s2 : c2;
    f *= ((r >> 2) & 1) ? s1 : c1;
    f *= ((r >> 3) & 1) ? s0 : c0;
    a[r].x = f;
    a[r].y = 0.f;
  }
}

// measurement (R4-verified logic; reduction via cheap-pipe wsum)
__device__ __forceinline__ void measure(const v2f a[16], int lane, float z[NQ]) {
  float p[16];
#pragma unroll
  for (int r = 0; r < 16; ++r) p[r] = a[r].x * a[r].x + a[r].y * a[r].y;
#pragma unroll
  for (int q = 0; q < 4; ++q) {
    const int rb = 3 - q;
    float acc = 0.f;
#pragma unroll
    for (int r = 0; r < 16; ++r) acc += ((r >> rb) & 1) ? -p[r] : p[r];
    z[q] = acc;
  }
  float P = 0.f;
#pragma unroll
  for (int r = 0; r < 16; ++r) P += p[r];
#pragma unroll
  for (int q = 4; q < NQ; ++q) {
    const int lb = 9 - q;
    z[q] = ((lane >> lb) & 1) ? -P : P;
  }
#pragma unroll
  for (int q = 0; q < NQ; ++q) z[q] = wsum(z[q]);
}

__global__ __launch_bounds__(256) void qsim_kernel(const float* __restrict__ x,
                                                   const float* __restrict__ w,
                                                   float* __restrict__ out,
                                                   int batch) {
  // ---- per-block: the 40 shared Rot matrices into LDS
  __shared__ __align__(16) float gsh[NL * NQ * 8];
  const int tid = threadIdx.x;
  if (tid < NL * NQ) {
    const float phi = w[tid * 3 + 0];
    const float th  = w[tid * 3 + 1];
    const float om  = w[tid * 3 + 2];
    float c, s, cp, sp, cm, sm;
    sincosf(0.5f * th, &s, &c);
    sincosf(-0.5f * (phi + om), &sp, &cp);
    sincosf(0.5f * (phi - om), &sm, &cm);
    float* g = &gsh[tid * 8];
    g[0] = cp * c;  g[1] = sp * c;    // u00
    g[2] = -cm * s; g[3] = -sm * s;   // u01
    g[4] = cm * s;  g[5] = -sm * s;   // u10
    g[6] = cp * c;  g[7] = -sp * c;   // u11
  }
  __syncthreads();

  const int samp = (int)(blockIdx.x * (blockDim.x >> 6)) + (tid >> 6);
  const int lane = tid & 63;
  if (samp >= batch) return;

  const int addr0 = 4 * (lane ^ (lane >> 1));
  const int addr1 = addr0 ^ 128;
  const bool lodd = (lane & 1);

  v2f a[16];
  encode(x + samp * NQ, lane, a);

  // ---- layers
#pragma unroll
  for (int l = 0; l < NL; ++l) {
    const float* gl = &gsh[l * NQ * 8];

    // qubits 0..3: register-bit gates
#pragma unroll
    for (int q = 0; q < 4; ++q) {
      const v2f* gv = (const v2f*)(gl + q * 8);
      const v2f u00 = gv[0], u01 = gv[1], u10 = gv[2], u11 = gv[3];
      if (q == 0)      gate_rbit<3>(a, u00, u01, u10, u11);
      else if (q == 1) gate_rbit<2>(a, u00, u01, u10, u11);
      else if (q == 2) gate_rbit<1>(a, u00, u01, u10, u11);
      else             gate_rbit<0>(a, u00, u01, u10, u11);
    }
    // qubit 4 (lane bit 5): permlane32_swap gate (VALU)
    {
      const v2f* gv = (const v2f*)(gl + 4 * 8);
      const bool hb = (lane >> 5) & 1;
      const v2f cL = hb ? gv[2] : gv[0];
      const v2f cH = hb ? gv[3] : gv[1];
      gate_swap<true>(a, cL, cH);
    }
    // qubit 5 (lane bit 4): permlane16_swap gate (VALU)
    {
      const v2f* gv = (const v2f*)(gl + 5 * 8);
      const bool hb = (lane >> 4) & 1;
      const v2f cL = hb ? gv[2] : gv[0];
      const v2f cH = hb ? gv[3] : gv[1];
      gate_swap<false>(a, cL, cH);
    }
    // qubits 6..9 (lane bits 3..0): partner gates (xor8/4 swizzle, xor2/1 DPP)
#pragma unroll
    for (int q = 6; q < 10; ++q) {
      const v2f* gv = (const v2f*)(gl + q * 8);
      const bool hb = (lane >> (9 - q)) & 1;
      const v2f cS = hb ? gv[3] : gv[0];
      const v2f cP = hb ? gv[2] : gv[1];
      if (q == 6)      gate_part<3>(a, cS, cP);
      else if (q == 7) gate_part<2>(a, cS, cP);
      else if (q == 8) gate_part<1>(a, cS, cP);
      else             gate_part<0>(a, cS, cP);
    }

    // entire CNOT ring as one permutation
    ring_comp(a, addr0, addr1, lodd);
  }

  // ---- measurement
  float z[NQ];
  measure(a, lane, z);

  if (lane == 0) {
#pragma unroll
    for (int q = 0; q < NQ; ++q) out[samp * NQ + q] = z[q];
  }
}

extern "C" void kernel_launch(void* const* d_in, const int* in_sizes, int n_in,
                              void* d_out, int out_size, void* d_ws, size_t ws_size,
                              hipStream_t stream) {
  const float* x = (const float*)d_in[0];
  const float* w = (const float*)d_in[1];
  float* out = (float*)d_out;
  const int batch = in_sizes[0] / NQ;
  const int waves_per_block = 256 / 64;
  const int grid = (batch + waves_per_block - 1) / waves_per_block;
  hipLaunchKernelGGL(qsim_kernel, dim3(grid), dim3(256), 0, stream, x, w, out, batch);
}